// Round 13
// baseline (335.896 us; speedup 1.0000x reference)
//
#include <hip/hip_runtime.h>
#include <hip/hip_bf16.h>
#include <math.h>

#define N 8192
#define F 133
#define FP 136
#define H 256
#define MF 200
#define RH 512
#define MAXDEG 128

typedef unsigned short bfu;

static __device__ __forceinline__ bfu f2bf(float f) {
    unsigned u = __builtin_bit_cast(unsigned, f);
    u = (u + 0x7fff + ((u >> 16) & 1)) >> 16;   // RNE, finite inputs
    return (bfu)u;
}
static __device__ __forceinline__ float bf2f(bfu b) {
    unsigned u = (unsigned)b << 16;
    return __builtin_bit_cast(float, u);
}

// ==== k_front: h0+scores0 (blocks 0..255) | A scan+extract (256..2303) ====
__global__ __launch_bounds__(256) void k_front(
    const float4* __restrict__ A4, int* __restrict__ cnt, int* __restrict__ colidx,
    const float* __restrict__ X, const float* __restrict__ Win,
    const float* __restrict__ bin, const float* __restrict__ Watt,
    bfu* __restrict__ hb, float* __restrict__ snei, float* __restrict__ sself) {
    const int t = threadIdx.x;
    const int b = blockIdx.x;
    if (b >= 256) {
        const int lane = t & 63;
        const int row = (b - 256) * 4 + (t >> 6);
        const float4* rowp = A4 + (size_t)row * (N / 4);
        unsigned w4[4];
#pragma unroll 1
        for (int c = 0; c < 4; ++c) {
            float4 v[8];
#pragma unroll
            for (int j = 0; j < 8; ++j) v[j] = rowp[c * 512 + j * 64 + lane];
            unsigned m = 0;
#pragma unroll
            for (int j = 0; j < 8; ++j) {
                const float* vp = &v[j].x;
#pragma unroll
                for (int q = 0; q < 4; ++q)
                    m |= (vp[q] != 0.0f) ? (1u << (j * 4 + q)) : 0u;
            }
            w4[c] = m;
        }
        int tl = __popc(w4[0]) + __popc(w4[1]) + __popc(w4[2]) + __popc(w4[3]);
        int inc = tl;
#pragma unroll
        for (int d = 1; d < 64; d <<= 1) {
            int nb = __shfl_up(inc, d);
            if (lane >= d) inc += nb;
        }
        int o = inc - tl;
        if (lane == 63) cnt[row] = inc < MAXDEG ? inc : MAXDEG;
        int* rowout = colidx + row * MAXDEG;
#pragma unroll
        for (int c = 0; c < 4; ++c) {
            unsigned m = w4[c];
            const int base = c * 2048 + lane * 4;
            while (m) {
                int p = __ffs(m) - 1;
                m &= m - 1;
                if (o < MAXDEG) rowout[o] = base + ((p >> 2) << 8) + (p & 3);
                ++o;
            }
        }
        return;
    }
    // ---------------- h0 = X @ W_in + b_in -> bf16, + scores of h0 ----------------
    __shared__ float xs[32][FP];
    __shared__ float sredN[32][4];
    __shared__ float sredS[32][4];
    const int row0 = b * 32;
    for (int i = t; i < 32 * F; i += 256) {
        int r = i / F, f = i - r * F;
        xs[r][f] = X[(row0 + r) * F + f];
    }
    __syncthreads();
    float acc[32];
#pragma unroll
    for (int r = 0; r < 32; ++r) acc[r] = 0.f;
    for (int f = 0; f < 132; f += 4) {
        float w0 = Win[(f + 0) * H + t];
        float w1 = Win[(f + 1) * H + t];
        float w2 = Win[(f + 2) * H + t];
        float w3 = Win[(f + 3) * H + t];
#pragma unroll
        for (int r = 0; r < 32; ++r) {
            float4 xv = *reinterpret_cast<const float4*>(&xs[r][f]);
            acc[r] = fmaf(xv.x, w0, acc[r]);
            acc[r] = fmaf(xv.y, w1, acc[r]);
            acc[r] = fmaf(xv.z, w2, acc[r]);
            acc[r] = fmaf(xv.w, w3, acc[r]);
        }
    }
    {
        float w0 = Win[132 * H + t];
#pragma unroll
        for (int r = 0; r < 32; ++r) acc[r] = fmaf(xs[r][132], w0, acc[r]);
    }
    const float bb = bin[t];
    const float wan = Watt[t];
    const float was = Watt[H + t];
    const int wv = t >> 6, ln = t & 63;
#pragma unroll
    for (int r = 0; r < 32; ++r) {
        float v = acc[r] + bb;
        hb[(row0 + r) * H + t] = f2bf(v);
        float pn = v * wan;
        float ps = v * was;
        for (int off = 32; off > 0; off >>= 1) {
            pn += __shfl_down(pn, off);
            ps += __shfl_down(ps, off);
        }
        if (ln == 0) { sredN[r][wv] = pn; sredS[r][wv] = ps; }
    }
    __syncthreads();
    if (t < 32)
        snei[row0 + t] = (sredN[t][0] + sredN[t][1]) + (sredN[t][2] + sredN[t][3]);
    else if (t < 64) {
        int r = t - 32;
        sself[row0 + r] = (sredS[r][0] + sredS[r][1]) + (sredS[r][2] + sredS[r][3]);
    }
}

// ==== k_depth: fused sigmoid-weights -> gather(LDS) -> GEMM(W staged in LDS)
//      -> relu+bias -> bf16 store + scores | colsum.  32 rows/block, 512 thr. ====
template <bool LAST>
__global__ __launch_bounds__(512, 2) void k_depth(
    const bfu* __restrict__ hin, bfu* __restrict__ hout,
    const int* __restrict__ cnt, const int* __restrict__ colidx,
    const float* __restrict__ snei_in, const float* __restrict__ sself_in,
    float* __restrict__ snei_out, float* __restrict__ sself_out,
    const float* __restrict__ Wn, const float* __restrict__ bn,
    const float* __restrict__ Watt, const float* __restrict__ b_att,
    float* __restrict__ part) {
    __shared__ float hs[32][260];      // 33.3 KB gathered rows (fp32)
    __shared__ float uni[8192];        // 32 KB: wls[4096]+jls_u16 (gather) / Ws (GEMM)
    __shared__ float sred[8 * 256];    // 8 KB (LAST colsum)
    __shared__ float sselfL[32];
    __shared__ int   ncnt[32];
    const int t = threadIdx.x;          // 0..511
    const int w = t >> 6, l = t & 63;   // 8 waves
    const int c0 = l << 2;
    const int R0 = blockIdx.x * 32;
    float* wls = uni;
    unsigned short* jls = (unsigned short*)(uni + 4096);

    if (t < 32) { ncnt[t] = cnt[R0 + t]; sselfL[t] = sself_in[R0 + t] + b_att[0]; }
    __syncthreads();
    // ---- phase 0: sigmoid weights (32 rows x 128) ----
#pragma unroll
    for (int rep = 0; rep < 8; ++rep) {
        int idx = t + rep * 512;
        int r = idx >> 7, k = idx & 127;
        if (k < ncnt[r]) {
            int j = colidx[(R0 + r) * MAXDEG + k];
            jls[idx] = (unsigned short)j;
            wls[idx] = 1.f / (1.f + __expf(-(sselfL[r] + snei_in[j])));
        }
    }
    __syncthreads();
    // ---- phase 1: gather; wave w owns rows 4w..4w+3 ----
#define GSTEP(u, sx, sy, sz, sw)                                                  \
    { int ju = (int)jls[r * 128 + k + u]; float wv = wls[r * 128 + k + u];        \
      ushort4 hv = *reinterpret_cast<const ushort4*>(&hin[ju * 256 + c0]);        \
      sx = fmaf(wv, bf2f(hv.x), sx); sy = fmaf(wv, bf2f(hv.y), sy);               \
      sz = fmaf(wv, bf2f(hv.z), sz); sw = fmaf(wv, bf2f(hv.w), sw); }
#pragma unroll 1
    for (int rr = 0; rr < 4; ++rr) {
        const int r = w * 4 + rr;
        const int n = ncnt[r];
        float x0=0,y0=0,z0=0,w0=0, x1=0,y1=0,z1=0,w1=0;
        float x2=0,y2=0,z2=0,w2=0, x3=0,y3=0,z3=0,w3=0;
        float x4=0,y4=0,z4=0,w4=0, x5=0,y5=0,z5=0,w5=0;
        float x6=0,y6=0,z6=0,w6=0, x7=0,y7=0,z7=0,w7=0;
        int k = 0;
        for (; k + 8 <= n; k += 8) {
            GSTEP(0,x0,y0,z0,w0) GSTEP(1,x1,y1,z1,w1)
            GSTEP(2,x2,y2,z2,w2) GSTEP(3,x3,y3,z3,w3)
            GSTEP(4,x4,y4,z4,w4) GSTEP(5,x5,y5,z5,w5)
            GSTEP(6,x6,y6,z6,w6) GSTEP(7,x7,y7,z7,w7)
        }
        for (; k < n; ++k) { GSTEP(0,x0,y0,z0,w0) }
        float4 st;
        st.x = ((x0+x1)+(x2+x3)) + ((x4+x5)+(x6+x7));
        st.y = ((y0+y1)+(y2+y3)) + ((y4+y5)+(y6+y7));
        st.z = ((z0+z1)+(z2+z3)) + ((z4+z5)+(z6+z7));
        st.w = ((w0+w1)+(w2+w3)) + ((w4+w5)+(w6+w7));
        *reinterpret_cast<float4*>(&hs[r][c0]) = st;
    }
#undef GSTEP
    __syncthreads();   // hs ready; wls/jls dead -> uni becomes Ws

    // ---- phase 2: GEMM 32x256 = hs @ Wn, W staged in LDS 32-k rows at a time ----
    float* Ws = uni;   // [32][256]
    float acc[4][4];
#pragma unroll
    for (int i = 0; i < 4; ++i)
#pragma unroll
        for (int j = 0; j < 4; ++j) acc[i][j] = 0.f;
#pragma unroll 1
    for (int k0 = 0; k0 < 8; ++k0) {
        if (k0) __syncthreads();
#pragma unroll
        for (int j = 0; j < 4; ++j) {
            int idx = j * 512 + t;            // 0..2047
            int kr = idx >> 6;                // 0..31
            int nc = (idx & 63) << 2;
            *reinterpret_cast<float4*>(&Ws[kr * 256 + nc]) =
                *reinterpret_cast<const float4*>(&Wn[(k0 * 32 + kr) * 256 + nc]);
        }
        __syncthreads();
#pragma unroll
        for (int k4 = 0; k4 < 8; ++k4) {
            float4 a0 = *reinterpret_cast<const float4*>(&hs[w * 4 + 0][k0 * 32 + k4 * 4]);
            float4 a1 = *reinterpret_cast<const float4*>(&hs[w * 4 + 1][k0 * 32 + k4 * 4]);
            float4 a2 = *reinterpret_cast<const float4*>(&hs[w * 4 + 2][k0 * 32 + k4 * 4]);
            float4 a3 = *reinterpret_cast<const float4*>(&hs[w * 4 + 3][k0 * 32 + k4 * 4]);
            const float* p0 = &a0.x;
            const float* p1 = &a1.x;
            const float* p2 = &a2.x;
            const float* p3 = &a3.x;
#pragma unroll
            for (int ki = 0; ki < 4; ++ki) {
                float4 wv = *reinterpret_cast<const float4*>(&Ws[(k4 * 4 + ki) * 256 + c0]);
                float aa0 = p0[ki], aa1 = p1[ki], aa2 = p2[ki], aa3 = p3[ki];
                acc[0][0] = fmaf(aa0, wv.x, acc[0][0]); acc[0][1] = fmaf(aa0, wv.y, acc[0][1]);
                acc[0][2] = fmaf(aa0, wv.z, acc[0][2]); acc[0][3] = fmaf(aa0, wv.w, acc[0][3]);
                acc[1][0] = fmaf(aa1, wv.x, acc[1][0]); acc[1][1] = fmaf(aa1, wv.y, acc[1][1]);
                acc[1][2] = fmaf(aa1, wv.z, acc[1][2]); acc[1][3] = fmaf(aa1, wv.w, acc[1][3]);
                acc[2][0] = fmaf(aa2, wv.x, acc[2][0]); acc[2][1] = fmaf(aa2, wv.y, acc[2][1]);
                acc[2][2] = fmaf(aa2, wv.z, acc[2][2]); acc[2][3] = fmaf(aa2, wv.w, acc[2][3]);
                acc[3][0] = fmaf(aa3, wv.x, acc[3][0]); acc[3][1] = fmaf(aa3, wv.y, acc[3][1]);
                acc[3][2] = fmaf(aa3, wv.z, acc[3][2]); acc[3][3] = fmaf(aa3, wv.w, acc[3][3]);
            }
        }
    }

    // ---- epilogue ----
    const float4 bv = *reinterpret_cast<const float4*>(&bn[c0]);
    float4 wanv, wasv;
    if (!LAST) {
        wanv = *reinterpret_cast<const float4*>(&Watt[c0]);
        wasv = *reinterpret_cast<const float4*>(&Watt[H + c0]);
    }
    float cs[4] = {0.f, 0.f, 0.f, 0.f};
#pragma unroll
    for (int i = 0; i < 4; ++i) {
        float v0 = acc[i][0] + bv.x; v0 = v0 > 0.f ? v0 : 0.f;
        float v1 = acc[i][1] + bv.y; v1 = v1 > 0.f ? v1 : 0.f;
        float v2 = acc[i][2] + bv.z; v2 = v2 > 0.f ? v2 : 0.f;
        float v3 = acc[i][3] + bv.w; v3 = v3 > 0.f ? v3 : 0.f;
        if (!LAST) {
            ushort4 o; o.x = f2bf(v0); o.y = f2bf(v1); o.z = f2bf(v2); o.w = f2bf(v3);
            *reinterpret_cast<ushort4*>(&hout[(R0 + w * 4 + i) * H + c0]) = o;
            float pn = v0 * wanv.x + v1 * wanv.y + v2 * wanv.z + v3 * wanv.w;
            float ps = v0 * wasv.x + v1 * wasv.y + v2 * wasv.z + v3 * wasv.w;
#pragma unroll
            for (int off = 32; off > 0; off >>= 1) {
                pn += __shfl_xor(pn, off);
                ps += __shfl_xor(ps, off);
            }
            if (l == 0) {
                snei_out[R0 + w * 4 + i] = pn;
                sself_out[R0 + w * 4 + i] = ps;
            }
        } else {
            cs[0] += v0; cs[1] += v1; cs[2] += v2; cs[3] += v3;
        }
    }
    if (LAST) {
#pragma unroll
        for (int j = 0; j < 4; ++j) sred[w * 256 + c0 + j] = cs[j];
        __syncthreads();
        if (t < 256) {
            float s = 0.f;
#pragma unroll
            for (int q = 0; q < 8; ++q) s += sred[q * 256 + t];
            part[blockIdx.x * 256 + t] = s;
        }
    }
}

// ==== readout tail: 8-block K-split kernels (proven R3 structure) ====
__global__ __launch_bounds__(256) void k_ro1(const float* __restrict__ part,
                                             const float* __restrict__ mol,
                                             const float* __restrict__ W,
                                             const float* __restrict__ b,
                                             const float* __restrict__ bo,
                                             float* __restrict__ g1,
                                             float* __restrict__ outsc) {
    __shared__ float xin[H + MF];
    __shared__ float red[256];
    const int t = threadIdx.x;
    {
        float s0 = 0.f, s1 = 0.f, s2 = 0.f, s3 = 0.f;
        float s4 = 0.f, s5 = 0.f, s6 = 0.f, s7 = 0.f;
        for (int r = 0; r < 256; r += 8) {
            s0 += part[(r + 0) * H + t];
            s1 += part[(r + 1) * H + t];
            s2 += part[(r + 2) * H + t];
            s3 += part[(r + 3) * H + t];
            s4 += part[(r + 4) * H + t];
            s5 += part[(r + 5) * H + t];
            s6 += part[(r + 6) * H + t];
            s7 += part[(r + 7) * H + t];
        }
        xin[t] = ((s0 + s1) + (s2 + s3)) + ((s4 + s5) + (s6 + s7));
    }
    if (t < MF) xin[H + t] = mol[t];
    if (blockIdx.x == 0 && t == 0) outsc[0] = bo[0];   // init for later atomics
    __syncthreads();
    const int o = blockIdx.x * 64 + (t & 63);
    const int kg = t >> 6;
    float acc = 0.f;
    for (int k = kg; k < H + MF; k += 4) acc = fmaf(xin[k], W[k * RH + o], acc);
    red[t] = acc;
    __syncthreads();
    if (t < 64) {
        float v = red[t] + red[t + 64] + red[t + 128] + red[t + 192] + b[o];
        g1[o] = v > 0.f ? v : 0.f;
    }
}

__global__ __launch_bounds__(256) void k_ro_hid(const float* __restrict__ g,
                                                const float* __restrict__ W,
                                                const float* __restrict__ b,
                                                float* __restrict__ out) {
    __shared__ float xin[RH];
    __shared__ float red[256];
    const int t = threadIdx.x;
    xin[t] = g[t];
    xin[t + 256] = g[t + 256];
    __syncthreads();
    const int o = blockIdx.x * 64 + (t & 63);
    const int kg = t >> 6;
    float acc = 0.f;
    for (int k = kg; k < RH; k += 4) acc = fmaf(xin[k], W[k * RH + o], acc);
    red[t] = acc;
    __syncthreads();
    if (t < 64) {
        float v = red[t] + red[t + 64] + red[t + 128] + red[t + 192] + b[o];
        out[o] = v > 0.f ? v : 0.f;
    }
}

__global__ __launch_bounds__(256) void k_ro_hid_dot(const float* __restrict__ g,
                                                    const float* __restrict__ W,
                                                    const float* __restrict__ b,
                                                    const float* __restrict__ Wo,
                                                    float* __restrict__ outsc) {
    __shared__ float xin[RH];
    __shared__ float red[256];
    const int t = threadIdx.x;
    xin[t] = g[t];
    xin[t + 256] = g[t + 256];
    __syncthreads();
    const int o = blockIdx.x * 64 + (t & 63);
    const int kg = t >> 6;
    float acc = 0.f;
    for (int k = kg; k < RH; k += 4) acc = fmaf(xin[k], W[k * RH + o], acc);
    red[t] = acc;
    __syncthreads();
    if (t < 64) {
        float v = red[t] + red[t + 64] + red[t + 128] + red[t + 192] + b[o];
        v = v > 0.f ? v : 0.f;
        float p = v * Wo[o];
#pragma unroll
        for (int off = 32; off > 0; off >>= 1) p += __shfl_down(p, off);
        if (t == 0) atomicAdd(outsc, p);
    }
}

extern "C" void kernel_launch(void* const* d_in, const int* in_sizes, int n_in,
                              void* d_out, int out_size, void* d_ws, size_t ws_size,
                              hipStream_t stream) {
    const float* A        = (const float*)d_in[0];
    const float* X        = (const float*)d_in[1];
    const float* mol      = (const float*)d_in[2];
    const float* W_in     = (const float*)d_in[3];
    const float* b_in     = (const float*)d_in[4];
    const float* W_att    = (const float*)d_in[5];
    const float* b_att    = (const float*)d_in[6];
    const float* W_node   = (const float*)d_in[7];
    const float* b_node   = (const float*)d_in[8];
    const float* W_ro_in  = (const float*)d_in[9];
    const float* b_ro_in  = (const float*)d_in[10];
    const float* W_ro_hid = (const float*)d_in[11];
    const float* b_ro_hid = (const float*)d_in[12];
    const float* W_out    = (const float*)d_in[13];
    const float* b_out    = (const float*)d_in[14];

    char* ws = (char*)d_ws;
    bfu*   hb_a   = (bfu*)  (ws);                        // 4 MB bf16 h
    bfu*   hb_b   = (bfu*)  (ws + 4194304);              // 4 MB
    int*   colidx = (int*)  (ws + 8388608);              // 4 MB
    int*   cnt    = (int*)  (ws + 12582912);             // 32 KB
    float* s0n    = (float*)(ws + 12615680);             // 32 KB
    float* s0s    = (float*)(ws + 12648448);             // 32 KB
    float* s1n    = (float*)(ws + 12681216);             // 32 KB
    float* s1s    = (float*)(ws + 12713984);             // 32 KB
    float* part   = (float*)(ws + 12746752);             // 256 KB (256x256)
    float* g1     = (float*)(ws + 13008896);             // 2 KB
    float* g2     = (float*)(ws + 13010944);             // 2 KB

    // front: h0+scores0 (blocks 0..255) | A scan+extract (256..2303)
    k_front<<<2304, 256, 0, stream>>>((const float4*)A, cnt, colidx,
                                      X, W_in, b_in, W_att, hb_a, s0n, s0s);
    // depth 0: a -> b
    k_depth<false><<<256, 512, 0, stream>>>(
        hb_a, hb_b, cnt, colidx, s0n, s0s, s1n, s1s,
        W_node + 0 * H * H, b_node + 0 * H, W_att, b_att, nullptr);
    // depth 1: b -> a
    k_depth<false><<<256, 512, 0, stream>>>(
        hb_b, hb_a, cnt, colidx, s1n, s1s, s0n, s0s,
        W_node + 1 * H * H, b_node + 1 * H, W_att, b_att, nullptr);
    // depth 2 (last): a -> part
    k_depth<true><<<256, 512, 0, stream>>>(
        hb_a, nullptr, cnt, colidx, s0n, s0s, nullptr, nullptr,
        W_node + 2 * H * H, b_node + 2 * H, W_att, b_att, part);
    // readout tail (fp32 exact)
    k_ro1<<<RH / 64, 256, 0, stream>>>(part, mol, W_ro_in, b_ro_in, b_out, g1,
                                       (float*)d_out);
    k_ro_hid<<<RH / 64, 256, 0, stream>>>(g1, W_ro_hid, b_ro_hid, g2);
    k_ro_hid_dot<<<RH / 64, 256, 0, stream>>>(g2, W_ro_hid + RH * RH, b_ro_hid + RH,
                                              W_out, (float*)d_out);
}

// Round 14
// 208.719 us; speedup vs baseline: 1.6093x; 1.6093x over previous
//
#include <hip/hip_runtime.h>
#include <hip/hip_bf16.h>
#include <math.h>

#define N 8192
#define F 133
#define FP 136
#define H 256
#define MF 200
#define RH 512
#define MAXDEG 128

typedef unsigned short bfu;

static __device__ __forceinline__ bfu f2bf(float f) {
    unsigned u = __builtin_bit_cast(unsigned, f);
    u = (u + 0x7fff + ((u >> 16) & 1)) >> 16;   // RNE, finite inputs
    return (bfu)u;
}
static __device__ __forceinline__ float bf2f(bfu b) {
    unsigned u = (unsigned)b << 16;
    return __builtin_bit_cast(float, u);
}

// ==== k_front: h0+scores0 (0..255) | A scan+extract (256..2303) | zero (2304) ====
__global__ __launch_bounds__(256) void k_front(
    const float4* __restrict__ A4, int* __restrict__ cnt, int* __restrict__ colidx,
    const float* __restrict__ X, const float* __restrict__ Win,
    const float* __restrict__ bin, const float* __restrict__ Watt,
    bfu* __restrict__ hb, float* __restrict__ snei, float* __restrict__ sself,
    float* __restrict__ zbuf) {
    const int t = threadIdx.x;
    const int b = blockIdx.x;
    if (b == 2304) {   // zero gsum(256)+g1p(512)+g2p(512)+g3p(512) = 1792 floats
        for (int i = t; i < 1792; i += 256) zbuf[i] = 0.f;
        return;
    }
    if (b >= 256) {
        const int lane = t & 63;
        const int row = (b - 256) * 4 + (t >> 6);
        const float4* rowp = A4 + (size_t)row * (N / 4);
        unsigned w4[4];
#pragma unroll 1
        for (int c = 0; c < 4; ++c) {
            float4 v[8];
#pragma unroll
            for (int j = 0; j < 8; ++j) v[j] = rowp[c * 512 + j * 64 + lane];
            unsigned m = 0;
#pragma unroll
            for (int j = 0; j < 8; ++j) {
                const float* vp = &v[j].x;
#pragma unroll
                for (int q = 0; q < 4; ++q)
                    m |= (vp[q] != 0.0f) ? (1u << (j * 4 + q)) : 0u;
            }
            w4[c] = m;
        }
        int tl = __popc(w4[0]) + __popc(w4[1]) + __popc(w4[2]) + __popc(w4[3]);
        int inc = tl;
#pragma unroll
        for (int d = 1; d < 64; d <<= 1) {
            int nb = __shfl_up(inc, d);
            if (lane >= d) inc += nb;
        }
        int o = inc - tl;
        if (lane == 63) cnt[row] = inc < MAXDEG ? inc : MAXDEG;
        int* rowout = colidx + row * MAXDEG;
#pragma unroll
        for (int c = 0; c < 4; ++c) {
            unsigned m = w4[c];
            const int base = c * 2048 + lane * 4;
            while (m) {
                int p = __ffs(m) - 1;
                m &= m - 1;
                if (o < MAXDEG) rowout[o] = base + ((p >> 2) << 8) + (p & 3);
                ++o;
            }
        }
        return;
    }
    // ---------------- h0 = X @ W_in + b_in -> bf16, + scores of h0 ----------------
    __shared__ float xs[32][FP];
    __shared__ float sredN[32][4];
    __shared__ float sredS[32][4];
    const int row0 = b * 32;
    for (int i = t; i < 32 * F; i += 256) {
        int r = i / F, f = i - r * F;
        xs[r][f] = X[(row0 + r) * F + f];
    }
    __syncthreads();
    float acc[32];
#pragma unroll
    for (int r = 0; r < 32; ++r) acc[r] = 0.f;
    for (int f = 0; f < 132; f += 4) {
        float w0 = Win[(f + 0) * H + t];
        float w1 = Win[(f + 1) * H + t];
        float w2 = Win[(f + 2) * H + t];
        float w3 = Win[(f + 3) * H + t];
#pragma unroll
        for (int r = 0; r < 32; ++r) {
            float4 xv = *reinterpret_cast<const float4*>(&xs[r][f]);
            acc[r] = fmaf(xv.x, w0, acc[r]);
            acc[r] = fmaf(xv.y, w1, acc[r]);
            acc[r] = fmaf(xv.z, w2, acc[r]);
            acc[r] = fmaf(xv.w, w3, acc[r]);
        }
    }
    {
        float w0 = Win[132 * H + t];
#pragma unroll
        for (int r = 0; r < 32; ++r) acc[r] = fmaf(xs[r][132], w0, acc[r]);
    }
    const float bb = bin[t];
    const float wan = Watt[t];
    const float was = Watt[H + t];
    const int wv = t >> 6, ln = t & 63;
#pragma unroll
    for (int r = 0; r < 32; ++r) {
        float v = acc[r] + bb;
        hb[(row0 + r) * H + t] = f2bf(v);
        float pn = v * wan;
        float ps = v * was;
        for (int off = 32; off > 0; off >>= 1) {
            pn += __shfl_down(pn, off);
            ps += __shfl_down(ps, off);
        }
        if (ln == 0) { sredN[r][wv] = pn; sredS[r][wv] = ps; }
    }
    __syncthreads();
    if (t < 32)
        snei[row0 + t] = (sredN[t][0] + sredN[t][1]) + (sredN[t][2] + sredN[t][3]);
    else if (t < 64) {
        int r = t - 32;
        sself[row0 + r] = (sredS[r][0] + sredS[r][1]) + (sredS[r][2] + sredS[r][3]);
    }
}

// ==== k_depth: fused weights -> gather(LDS) -> GEMM(W in LDS) -> epilogue ====
template <bool LAST>
__global__ __launch_bounds__(512, 2) void k_depth(
    const bfu* __restrict__ hin, bfu* __restrict__ hout,
    const int* __restrict__ cnt, const int* __restrict__ colidx,
    const float* __restrict__ snei_in, const float* __restrict__ sself_in,
    float* __restrict__ snei_out, float* __restrict__ sself_out,
    const float* __restrict__ Wn, const float* __restrict__ bn,
    const float* __restrict__ Watt, const float* __restrict__ b_att,
    float* __restrict__ gsum) {
    __shared__ float hs[32][260];
    __shared__ float uni[8192];
    __shared__ float sred[8 * 256];
    __shared__ float sselfL[32];
    __shared__ int   ncnt[32];
    const int t = threadIdx.x;
    const int w = t >> 6, l = t & 63;
    const int c0 = l << 2;
    const int R0 = blockIdx.x * 32;
    float* wls = uni;
    unsigned short* jls = (unsigned short*)(uni + 4096);

    if (t < 32) { ncnt[t] = cnt[R0 + t]; sselfL[t] = sself_in[R0 + t] + b_att[0]; }
    __syncthreads();
#pragma unroll
    for (int rep = 0; rep < 8; ++rep) {
        int idx = t + rep * 512;
        int r = idx >> 7, k = idx & 127;
        if (k < ncnt[r]) {
            int j = colidx[(R0 + r) * MAXDEG + k];
            jls[idx] = (unsigned short)j;
            wls[idx] = 1.f / (1.f + __expf(-(sselfL[r] + snei_in[j])));
        }
    }
    __syncthreads();
#define GSTEP(u, sx, sy, sz, sw)                                                  \
    { int ju = (int)jls[r * 128 + k + u]; float wv = wls[r * 128 + k + u];        \
      ushort4 hv = *reinterpret_cast<const ushort4*>(&hin[ju * 256 + c0]);        \
      sx = fmaf(wv, bf2f(hv.x), sx); sy = fmaf(wv, bf2f(hv.y), sy);               \
      sz = fmaf(wv, bf2f(hv.z), sz); sw = fmaf(wv, bf2f(hv.w), sw); }
#pragma unroll 1
    for (int rr = 0; rr < 4; ++rr) {
        const int r = w * 4 + rr;
        const int n = ncnt[r];
        float x0=0,y0=0,z0=0,w0=0, x1=0,y1=0,z1=0,w1=0;
        float x2=0,y2=0,z2=0,w2=0, x3=0,y3=0,z3=0,w3=0;
        float x4=0,y4=0,z4=0,w4=0, x5=0,y5=0,z5=0,w5=0;
        float x6=0,y6=0,z6=0,w6=0, x7=0,y7=0,z7=0,w7=0;
        int k = 0;
        for (; k + 8 <= n; k += 8) {
            GSTEP(0,x0,y0,z0,w0) GSTEP(1,x1,y1,z1,w1)
            GSTEP(2,x2,y2,z2,w2) GSTEP(3,x3,y3,z3,w3)
            GSTEP(4,x4,y4,z4,w4) GSTEP(5,x5,y5,z5,w5)
            GSTEP(6,x6,y6,z6,w6) GSTEP(7,x7,y7,z7,w7)
        }
        for (; k < n; ++k) { GSTEP(0,x0,y0,z0,w0) }
        float4 st;
        st.x = ((x0+x1)+(x2+x3)) + ((x4+x5)+(x6+x7));
        st.y = ((y0+y1)+(y2+y3)) + ((y4+y5)+(y6+y7));
        st.z = ((z0+z1)+(z2+z3)) + ((z4+z5)+(z6+z7));
        st.w = ((w0+w1)+(w2+w3)) + ((w4+w5)+(w6+w7));
        *reinterpret_cast<float4*>(&hs[r][c0]) = st;
    }
#undef GSTEP
    __syncthreads();

    float* Ws = uni;
    float acc[4][4];
#pragma unroll
    for (int i = 0; i < 4; ++i)
#pragma unroll
        for (int j = 0; j < 4; ++j) acc[i][j] = 0.f;
#pragma unroll 1
    for (int k0 = 0; k0 < 8; ++k0) {
        if (k0) __syncthreads();
#pragma unroll
        for (int j = 0; j < 4; ++j) {
            int idx = j * 512 + t;
            int kr = idx >> 6;
            int nc = (idx & 63) << 2;
            *reinterpret_cast<float4*>(&Ws[kr * 256 + nc]) =
                *reinterpret_cast<const float4*>(&Wn[(k0 * 32 + kr) * 256 + nc]);
        }
        __syncthreads();
#pragma unroll
        for (int k4 = 0; k4 < 8; ++k4) {
            float4 a0 = *reinterpret_cast<const float4*>(&hs[w * 4 + 0][k0 * 32 + k4 * 4]);
            float4 a1 = *reinterpret_cast<const float4*>(&hs[w * 4 + 1][k0 * 32 + k4 * 4]);
            float4 a2 = *reinterpret_cast<const float4*>(&hs[w * 4 + 2][k0 * 32 + k4 * 4]);
            float4 a3 = *reinterpret_cast<const float4*>(&hs[w * 4 + 3][k0 * 32 + k4 * 4]);
            const float* p0 = &a0.x;
            const float* p1 = &a1.x;
            const float* p2 = &a2.x;
            const float* p3 = &a3.x;
#pragma unroll
            for (int ki = 0; ki < 4; ++ki) {
                float4 wv = *reinterpret_cast<const float4*>(&Ws[(k4 * 4 + ki) * 256 + c0]);
                float aa0 = p0[ki], aa1 = p1[ki], aa2 = p2[ki], aa3 = p3[ki];
                acc[0][0] = fmaf(aa0, wv.x, acc[0][0]); acc[0][1] = fmaf(aa0, wv.y, acc[0][1]);
                acc[0][2] = fmaf(aa0, wv.z, acc[0][2]); acc[0][3] = fmaf(aa0, wv.w, acc[0][3]);
                acc[1][0] = fmaf(aa1, wv.x, acc[1][0]); acc[1][1] = fmaf(aa1, wv.y, acc[1][1]);
                acc[1][2] = fmaf(aa1, wv.z, acc[1][2]); acc[1][3] = fmaf(aa1, wv.w, acc[1][3]);
                acc[2][0] = fmaf(aa2, wv.x, acc[2][0]); acc[2][1] = fmaf(aa2, wv.y, acc[2][1]);
                acc[2][2] = fmaf(aa2, wv.z, acc[2][2]); acc[2][3] = fmaf(aa2, wv.w, acc[2][3]);
                acc[3][0] = fmaf(aa3, wv.x, acc[3][0]); acc[3][1] = fmaf(aa3, wv.y, acc[3][1]);
                acc[3][2] = fmaf(aa3, wv.z, acc[3][2]); acc[3][3] = fmaf(aa3, wv.w, acc[3][3]);
            }
        }
    }

    const float4 bv = *reinterpret_cast<const float4*>(&bn[c0]);
    float4 wanv, wasv;
    if (!LAST) {
        wanv = *reinterpret_cast<const float4*>(&Watt[c0]);
        wasv = *reinterpret_cast<const float4*>(&Watt[H + c0]);
    }
    float cs[4] = {0.f, 0.f, 0.f, 0.f};
#pragma unroll
    for (int i = 0; i < 4; ++i) {
        float v0 = acc[i][0] + bv.x; v0 = v0 > 0.f ? v0 : 0.f;
        float v1 = acc[i][1] + bv.y; v1 = v1 > 0.f ? v1 : 0.f;
        float v2 = acc[i][2] + bv.z; v2 = v2 > 0.f ? v2 : 0.f;
        float v3 = acc[i][3] + bv.w; v3 = v3 > 0.f ? v3 : 0.f;
        if (!LAST) {
            ushort4 o; o.x = f2bf(v0); o.y = f2bf(v1); o.z = f2bf(v2); o.w = f2bf(v3);
            *reinterpret_cast<ushort4*>(&hout[(R0 + w * 4 + i) * H + c0]) = o;
            float pn = v0 * wanv.x + v1 * wanv.y + v2 * wanv.z + v3 * wanv.w;
            float ps = v0 * wasv.x + v1 * wasv.y + v2 * wasv.z + v3 * wasv.w;
#pragma unroll
            for (int off = 32; off > 0; off >>= 1) {
                pn += __shfl_xor(pn, off);
                ps += __shfl_xor(ps, off);
            }
            if (l == 0) {
                snei_out[R0 + w * 4 + i] = pn;
                sself_out[R0 + w * 4 + i] = ps;
            }
        } else {
            cs[0] += v0; cs[1] += v1; cs[2] += v2; cs[3] += v3;
        }
    }
    if (LAST) {
#pragma unroll
        for (int j = 0; j < 4; ++j) sred[w * 256 + c0 + j] = cs[j];
        __syncthreads();
        if (t < 256) {
            float s = 0.f;
#pragma unroll
            for (int q = 0; q < 8; ++q) s += sred[q * 256 + t];
            atomicAdd(&gsum[t], s);
        }
    }
}

// ==== k_t: readout GEMV layer, 64 blocks = 8 o-groups x 8 K-slices ====
// MODE 0: x = [gsum, mol], K=456.  MODE 1: x = relu(xsrc + bp), K=512.
// Partial sums atomicAdd'ed into pre-zeroed pout; bias applied by consumer.
template <int MODE>
__global__ __launch_bounds__(256) void k_t(const float* __restrict__ xsrc,
                                           const float* __restrict__ bp,
                                           const float* __restrict__ mol,
                                           const float* __restrict__ W,
                                           float* __restrict__ pout) {
    const int K = (MODE == 0) ? (H + MF) : RH;
    const int KW = K / 8;                 // 57 or 64
    const int lo = blockIdx.y * KW;
    __shared__ float xin[64];
    __shared__ float red[256];
    const int t = threadIdx.x;
    if (t < KW) {
        int k = lo + t;
        float xv;
        if (MODE == 0) xv = (k < H) ? xsrc[k] : mol[k - H];
        else {
            float p = xsrc[k] + bp[k];
            xv = p > 0.f ? p : 0.f;
        }
        xin[t] = xv;
    }
    __syncthreads();
    const int o = blockIdx.x * 64 + (t & 63);
    const int kg = t >> 6;
    float acc = 0.f;
    for (int k = kg; k < KW; k += 4)
        acc = fmaf(xin[k], W[(lo + k) * RH + o], acc);
    red[t] = acc;
    __syncthreads();
    if (t < 64) {
        float s = red[t] + red[t + 64] + red[t + 128] + red[t + 192];
        atomicAdd(&pout[o], s);
    }
}

// ==== k_fin: out = b_out + sum_o relu(g3p[o] + b3[o]) * Wo[o] ====
__global__ __launch_bounds__(512) void k_fin(const float* __restrict__ g3p,
                                             const float* __restrict__ b3,
                                             const float* __restrict__ Wo,
                                             const float* __restrict__ bo,
                                             float* __restrict__ out) {
    __shared__ float red[512];
    const int t = threadIdx.x;
    float v = g3p[t] + b3[t];
    v = v > 0.f ? v : 0.f;
    red[t] = v * Wo[t];
    __syncthreads();
    for (int s = 256; s > 0; s >>= 1) {
        if (t < s) red[t] += red[t + s];
        __syncthreads();
    }
    if (t == 0) out[0] = red[0] + bo[0];
}

extern "C" void kernel_launch(void* const* d_in, const int* in_sizes, int n_in,
                              void* d_out, int out_size, void* d_ws, size_t ws_size,
                              hipStream_t stream) {
    const float* A        = (const float*)d_in[0];
    const float* X        = (const float*)d_in[1];
    const float* mol      = (const float*)d_in[2];
    const float* W_in     = (const float*)d_in[3];
    const float* b_in     = (const float*)d_in[4];
    const float* W_att    = (const float*)d_in[5];
    const float* b_att    = (const float*)d_in[6];
    const float* W_node   = (const float*)d_in[7];
    const float* b_node   = (const float*)d_in[8];
    const float* W_ro_in  = (const float*)d_in[9];
    const float* b_ro_in  = (const float*)d_in[10];
    const float* W_ro_hid = (const float*)d_in[11];
    const float* b_ro_hid = (const float*)d_in[12];
    const float* W_out    = (const float*)d_in[13];
    const float* b_out    = (const float*)d_in[14];

    char* ws = (char*)d_ws;
    bfu*   hb_a   = (bfu*)  (ws);                        // 4 MB bf16 h
    bfu*   hb_b   = (bfu*)  (ws + 4194304);              // 4 MB
    int*   colidx = (int*)  (ws + 8388608);              // 4 MB
    int*   cnt    = (int*)  (ws + 12582912);             // 32 KB
    float* s0n    = (float*)(ws + 12615680);             // 32 KB
    float* s0s    = (float*)(ws + 12648448);             // 32 KB
    float* s1n    = (float*)(ws + 12681216);             // 32 KB
    float* s1s    = (float*)(ws + 12713984);             // 32 KB
    float* zbuf   = (float*)(ws + 12746752);             // 1792 floats: gsum|g1p|g2p|g3p
    float* gsum   = zbuf;
    float* g1p    = zbuf + 256;
    float* g2p    = zbuf + 768;
    float* g3p    = zbuf + 1280;

    // front: h0+scores0 (0..255) | scan+extract (256..2303) | zero bufs (2304)
    k_front<<<2305, 256, 0, stream>>>((const float4*)A, cnt, colidx,
                                      X, W_in, b_in, W_att, hb_a, s0n, s0s, zbuf);
    // depth 0: a -> b
    k_depth<false><<<256, 512, 0, stream>>>(
        hb_a, hb_b, cnt, colidx, s0n, s0s, s1n, s1s,
        W_node + 0 * H * H, b_node + 0 * H, W_att, b_att, nullptr);
    // depth 1: b -> a
    k_depth<false><<<256, 512, 0, stream>>>(
        hb_b, hb_a, cnt, colidx, s1n, s1s, s0n, s0s,
        W_node + 1 * H * H, b_node + 1 * H, W_att, b_att, nullptr);
    // depth 2 (last): a -> gsum (atomic colsum)
    k_depth<true><<<256, 512, 0, stream>>>(
        hb_a, nullptr, cnt, colidx, s0n, s0s, nullptr, nullptr,
        W_node + 2 * H * H, b_node + 2 * H, W_att, b_att, gsum);
    // readout: 64-block K-split GEMV per layer, bias+relu folded into consumer
    k_t<0><<<dim3(8, 8), 256, 0, stream>>>(gsum, nullptr, mol, W_ro_in, g1p);
    k_t<1><<<dim3(8, 8), 256, 0, stream>>>(g1p, b_ro_in, nullptr, W_ro_hid, g2p);
    k_t<1><<<dim3(8, 8), 256, 0, stream>>>(g2p, b_ro_hid, nullptr,
                                           W_ro_hid + RH * RH, g3p);
    k_fin<<<1, 512, 0, stream>>>(g3p, b_ro_hid + RH, W_out, b_out, (float*)d_out);
}